// Round 5
// baseline (46.274 us; speedup 1.0000x reference)
//
#include <hip/hip_runtime.h>

#pragma clang fp contract(off)

#define HH 256
#define WW 256
#define TILE 8
#define NTX (WW / TILE)   // 32
#define NTY (HH / TILE)   // 32
#define NT (NTX * NTY)    // 1024
#define CHUNK_F 256
#define KWAY 4            // threads per pixel
#define BLK 256           // 64 pixels * KWAY
#define BIGF 1000000.0f
#define EPSF 1e-12f

__global__ void zero_counts(int* counts) {
    int i = blockIdx.x * blockDim.x + threadIdx.x;
    if (i < NT) counts[i] = 0;
}

// Bin faces into 8x8-pixel tiles by conservative bbox (+1 px margin).
// Degenerate faces (|d| < EPS -> d=EPS in reference) can pass the inside test
// anywhere along their line: broadcast those to every tile (rare, safe).
__global__ void bin_faces(const float* __restrict__ fv, int F,
                          int* __restrict__ counts, int* __restrict__ lists, int cap) {
#pragma clang fp contract(off)
    int f = blockIdx.x * blockDim.x + threadIdx.x;
    if (f >= F) return;
    const float* v = fv + (size_t)f * 9;
    float x0 = v[0], y0 = v[1];
    float x1 = v[3], y1 = v[4];
    float x2 = v[6], y2 = v[7];
    float A = y1 - y2;
    float Bc = x2 - x1;
    float D = x0 - x2;
    float E = y0 - y2;
    float t = A * D;
    float u = Bc * E;
    float d = t + u;
    int tx0, tx1, ty0, ty1;
    if (fabsf(d) < EPSF) {
        tx0 = 0; tx1 = NTX - 1; ty0 = 0; ty1 = NTY - 1;
    } else {
        float minx = fminf(x0, fminf(x1, x2)) - 1.0f;
        float maxx = fmaxf(x0, fmaxf(x1, x2)) + 1.0f;
        float miny = fminf(y0, fminf(y1, y2)) - 1.0f;
        float maxy = fmaxf(y0, fmaxf(y1, y2)) + 1.0f;
        int px0 = (int)floorf(minx), px1 = (int)floorf(maxx);
        int py0 = (int)floorf(miny), py1 = (int)floorf(maxy);
        if (px1 < 0 || py1 < 0 || px0 > WW - 1 || py0 > HH - 1) return;
        px0 = max(px0, 0); py0 = max(py0, 0);
        px1 = min(px1, WW - 1); py1 = min(py1, HH - 1);
        tx0 = px0 / TILE; tx1 = px1 / TILE;
        ty0 = py0 / TILE; ty1 = py1 / TILE;
    }
    for (int ty = ty0; ty <= ty1; ++ty)
        for (int tx = tx0; tx <= tx1; ++tx) {
            int tIdx = ty * NTX + tx;
            int pos = atomicAdd(&counts[tIdx], 1);
            if (pos < cap) lists[(size_t)tIdx * cap + pos] = f;
        }
}

// One block per 8x8 tile. 256 threads = 4 waves; tid = k*64 + pix, so each
// wave is one k-slice: all 64 lanes (one per pixel) read the SAME staged face
// (LDS broadcast) and each k-slice covers a strided 1/4 of the face list.
// Winner = min over packed (depth_bits<<32 | id) == reference lexicographic
// (depth, id) winner. Sign-based early-out skips the IEEE divides for faces
// that cannot have w0>=0 && w1>=0 (sign of a quotient is exact).
// __launch_bounds__(256,4): 4 blocks/CU -> all 1024 blocks resident in one
// pass with VGPR budget <=128 (no spill pressure).
__global__ __launch_bounds__(BLK, 4) void raster_shade(
    const float* __restrict__ fv, const float* __restrict__ fc,
    int F, const int* __restrict__ counts, const int* __restrict__ lists, int cap,
    float* __restrict__ out, int write_bufs) {
#pragma clang fp contract(off)
    __shared__ float4 sE[CHUNK_F];                 // A, B, C, D
    __shared__ float4 sP[CHUNK_F];                 // x2, y2, d, id(bits)
    __shared__ float4 sZ[CHUNK_F];                 // z0, z1, z2, -
    __shared__ unsigned long long red[BLK];

    int tIdx = blockIdx.x;
    int tx = tIdx % NTX, ty = tIdx / NTX;
    int tid = threadIdx.x;
    int pix = tid & 63;
    int k = tid >> 6;
    float gx = (float)(tx * TILE + (pix & 7)) + 0.5f;
    float gy = (float)(ty * TILE + (pix >> 3)) + 0.5f;

    int count = counts[tIdx];
    bool list_ok = (count <= cap);                 // overflow -> brute force
    int total = list_ok ? count : F;

    unsigned long long best =
        ((unsigned long long)__float_as_uint(BIGF) << 32) | 0xFFFFFFFFull;

    for (int base = 0; base < total; base += CHUNK_F) {
        int n = min(CHUNK_F, total - base);
        if (tid < n) {
            int f = list_ok ? lists[(size_t)tIdx * cap + base + tid] : (base + tid);
            const float* v = fv + (size_t)f * 9;
            float x0 = v[0], y0 = v[1], z0 = v[2];
            float x1 = v[3], y1 = v[4], z1 = v[5];
            float x2 = v[6], y2 = v[7], z2 = v[8];
            float A = y1 - y2;
            float Bc = x2 - x1;
            float C = y2 - y0;
            float D = x0 - x2;
            float E = y0 - y2;
            float t = A * D;
            float u = Bc * E;
            float d = t + u;
            if (fabsf(d) < EPSF) d = EPSF;
            sE[tid] = make_float4(A, Bc, C, D);
            sP[tid] = make_float4(x2, y2, d, __int_as_float(f));
            sZ[tid] = make_float4(z0, z1, z2, 0.0f);
        }
        __syncthreads();
        for (int j = k; j < n; j += KWAY) {
            float4 Ef = sE[j];
            float4 Pf = sP[j];
            float dx = gx - Pf.x;
            float dy = gy - Pf.y;
            float n0 = Ef.x * dx + Ef.y * dy;   // contract off: mul,mul,add
            float n1 = Ef.z * dx + Ef.w * dy;
            unsigned du = __float_as_uint(Pf.z);
            // w0>=0 iff n0==+-0 (quotient +-0 passes >=0) or sign(n0)==sign(d)
            bool ok0 = (n0 == 0.0f) || (((__float_as_uint(n0) ^ du) >> 31) == 0u);
            bool ok1 = (n1 == 0.0f) || (((__float_as_uint(n1) ^ du) >> 31) == 0u);
            if (ok0 && ok1) {
                float w0 = n0 / Pf.z;
                float w1 = n1 / Pf.z;
                float w2 = (1.0f - w0) - w1;
                if (w2 >= 0.0f) {
                    float4 Zf = sZ[j];
                    float inv = (w0 / Zf.x + w1 / Zf.y) + w2 / Zf.z;
                    float depth = 1.0f / inv;
                    unsigned id = (unsigned)__float_as_int(Pf.w);
                    unsigned long long cand =
                        ((unsigned long long)__float_as_uint(depth) << 32) | id;
                    if (cand < best) best = cand;
                }
            }
        }
        __syncthreads();
    }

    red[tid] = best;
    __syncthreads();
    for (int s = BLK / 2; s >= 64; s >>= 1) {
        if (tid < s) {
            unsigned long long o = red[tid + s];
            if (o < red[tid]) red[tid] = o;
        }
        __syncthreads();
    }

    if (tid < 64) {
        best = red[tid];
        int bestId = (int)(unsigned)best;          // 0xFFFFFFFF -> -1
        int px = tx * TILE + (tid & 7);
        int py = ty * TILE + (tid >> 3);
        int pixidx = py * WW + px;
        float r = 0.0f, g = 0.0f, b = 0.0f;
        float depthOut = BIGF;
        if (bestId >= 0) {
            const float* v = fv + (size_t)bestId * 9;
            float x0 = v[0], y0 = v[1], z0 = v[2];
            float x1 = v[3], y1 = v[4], z1 = v[5];
            float x2 = v[6], y2 = v[7], z2 = v[8];
            float A = y1 - y2;
            float Bc = x2 - x1;
            float C = y2 - y0;
            float D = x0 - x2;
            float E = y0 - y2;
            float t = A * D;
            float u = Bc * E;
            float d = t + u;
            if (fabsf(d) < EPSF) d = EPSF;
            float dx = gx - x2;
            float dy = gy - y2;
            float n0 = A * dx + Bc * dy;
            float w0 = n0 / d;
            float n1 = C * dx + D * dy;
            float w1 = n1 / d;
            float w2 = (1.0f - w0) - w1;
            float wc0 = w0 / z0, wc1 = w1 / z1, wc2 = w2 / z2;
            float s2 = (wc0 + wc1) + wc2;
            wc0 = wc0 / s2; wc1 = wc1 / s2; wc2 = wc2 / s2;
            const float* c = fc + (size_t)bestId * 9;
            r = (wc0 * c[0] + wc1 * c[3]) + wc2 * c[6];
            g = (wc0 * c[1] + wc1 * c[4]) + wc2 * c[7];
            b = (wc0 * c[2] + wc1 * c[5]) + wc2 * c[8];
            depthOut = (wc0 * z0 + wc1 * z1) + wc2 * z2;
        }
        out[0 * HH * WW + pixidx] = r;
        out[1 * HH * WW + pixidx] = g;
        out[2 * HH * WW + pixidx] = b;
        if (write_bufs) {
            out[3 * HH * WW + pixidx] = (float)bestId;
            out[4 * HH * WW + pixidx] = depthOut;
        }
    }
}

extern "C" void kernel_launch(void* const* d_in, const int* in_sizes, int n_in,
                              void* d_out, int out_size, void* d_ws, size_t ws_size,
                              hipStream_t stream) {
    const float* fv = (const float*)d_in[0];
    const float* fc = (const float*)d_in[1];
    int F = in_sizes[0] / 9;
    float* out = (float*)d_out;
    int write_bufs = (out_size >= 5 * HH * WW) ? 1 : 0;

    int* counts = (int*)d_ws;                      // NT ints = 4 KB
    size_t hdr = 8192;
    size_t avail_ints = (ws_size > hdr) ? (ws_size - hdr) / 4 : 0;
    long cap_l = (long)(avail_ints / NT);
    int cap = (int)((cap_l < (long)F) ? cap_l : (long)F);
    int* lists = nullptr;
    if (cap >= 32) {
        lists = (int*)((char*)d_ws + hdr);
    } else {
        cap = 0;  // brute force over all faces per tile
    }

    zero_counts<<<(NT + 255) / 256, 256, 0, stream>>>(counts);
    if (lists) bin_faces<<<(F + 255) / 256, 256, 0, stream>>>(fv, F, counts, lists, cap);
    raster_shade<<<NT, BLK, 0, stream>>>(fv, fc, F, counts, lists, cap, out, write_bufs);
}

// Round 6
// 22.318 us; speedup vs baseline: 2.0734x; 2.0734x over previous
//
#include <hip/hip_runtime.h>

#pragma clang fp contract(off)

#define HH 256
#define WW 256
#define BIGF 1000000.0f
#define EPSF 1e-12f

// One wave per face. Lanes sweep the face's conservative bbox (+1 px margin,
// matches point-in-hull for all-w>=0); degenerate faces (|d|<EPS -> d=EPS in
// reference) sweep the full screen (their inside set can lie anywhere on a
// line). Inside test replicates reference f32 op order exactly (contract off,
// sign-gate == sign of IEEE quotient). Winner = min packed (depth_bits<<32|id)
// == reference lexicographic (depth, id) argmin, merged via u64 atomicMin.
__global__ __launch_bounds__(256) void scatter_faces(
    const float* __restrict__ fv, int F, unsigned long long* __restrict__ pixbuf) {
#pragma clang fp contract(off)
    int gw = (int)((blockIdx.x * blockDim.x + threadIdx.x) >> 6);  // wave id = face
    int lane = threadIdx.x & 63;
    if (gw >= F) return;
    const float* v = fv + (size_t)gw * 9;
    float x0 = v[0], y0 = v[1];
    float x1 = v[3], y1 = v[4], z1 = v[5];
    float x2 = v[6], y2 = v[7], z2 = v[8];
    float z0 = v[2];
    float A = y1 - y2;
    float Bc = x2 - x1;
    float C = y2 - y0;
    float D = x0 - x2;
    float E = y0 - y2;
    float t = A * D;
    float u = Bc * E;
    float d = t + u;
    int px0, px1, py0, py1;
    if (fabsf(d) < EPSF) {
        d = EPSF;
        px0 = 0; px1 = WW - 1; py0 = 0; py1 = HH - 1;
    } else {
        float minx = fminf(x0, fminf(x1, x2)) - 1.0f;
        float maxx = fmaxf(x0, fmaxf(x1, x2)) + 1.0f;
        float miny = fminf(y0, fminf(y1, y2)) - 1.0f;
        float maxy = fmaxf(y0, fmaxf(y1, y2)) + 1.0f;
        px0 = (int)floorf(minx); px1 = (int)floorf(maxx);
        py0 = (int)floorf(miny); py1 = (int)floorf(maxy);
        if (px1 < 0 || py1 < 0 || px0 > WW - 1 || py0 > HH - 1) return;
        px0 = max(px0, 0); py0 = max(py0, 0);
        px1 = min(px1, WW - 1); py1 = min(py1, HH - 1);
    }
    int w = px1 - px0 + 1;
    int h = py1 - py0 + 1;
    int npx = w * h;
    unsigned du = __float_as_uint(d);
    for (int i = lane; i < npx; i += 64) {
        int px = px0 + i % w;
        int py = py0 + i / w;
        float gx = (float)px + 0.5f;
        float gy = (float)py + 0.5f;
        float dx = gx - x2;
        float dy = gy - y2;
        float n0 = A * dx + Bc * dy;   // contract off: mul,mul,add (RNE)
        float n1 = C * dx + D * dy;
        // w0>=0 iff n0==+-0 (quotient +-0 passes >=0) or sign(n0)==sign(d)
        bool ok0 = (n0 == 0.0f) || (((__float_as_uint(n0) ^ du) >> 31) == 0u);
        bool ok1 = (n1 == 0.0f) || (((__float_as_uint(n1) ^ du) >> 31) == 0u);
        if (ok0 && ok1) {
            float w0 = n0 / d;
            float w1 = n1 / d;
            float w2 = (1.0f - w0) - w1;
            if (w2 >= 0.0f) {
                float inv = (w0 / z0 + w1 / z1) + w2 / z2;
                float depth = 1.0f / inv;
                unsigned long long cand =
                    ((unsigned long long)__float_as_uint(depth) << 32) | (unsigned)gw;
                atomicMin(&pixbuf[py * WW + px], cand);
            }
        }
    }
}

// One thread per pixel; coalesced pixbuf read and plane writes.
// Shade replicates reference _shade (exact op order; precision slack is huge
// here anyway — only hit/miss classification is threshold-critical).
__global__ __launch_bounds__(256) void shade(
    const float* __restrict__ fv, const float* __restrict__ fc,
    const unsigned long long* __restrict__ pixbuf,
    float* __restrict__ out, int write_bufs) {
#pragma clang fp contract(off)
    int p = blockIdx.x * blockDim.x + threadIdx.x;
    if (p >= HH * WW) return;
    unsigned long long best = pixbuf[p];
    int bestId = (int)(unsigned)best;   // sentinel low32 has sign bit set -> <0
    float gx = (float)(p % WW) + 0.5f;
    float gy = (float)(p / WW) + 0.5f;
    float r = 0.0f, g = 0.0f, b = 0.0f;
    float depthOut = BIGF;
    if (bestId >= 0) {
        const float* v = fv + (size_t)bestId * 9;
        float x0 = v[0], y0 = v[1], z0 = v[2];
        float x1 = v[3], y1 = v[4], z1 = v[5];
        float x2 = v[6], y2 = v[7], z2 = v[8];
        float A = y1 - y2;
        float Bc = x2 - x1;
        float C = y2 - y0;
        float D = x0 - x2;
        float E = y0 - y2;
        float t = A * D;
        float u = Bc * E;
        float d = t + u;
        if (fabsf(d) < EPSF) d = EPSF;
        float dx = gx - x2;
        float dy = gy - y2;
        float n0 = A * dx + Bc * dy;
        float w0 = n0 / d;
        float n1 = C * dx + D * dy;
        float w1 = n1 / d;
        float w2 = (1.0f - w0) - w1;
        float wc0 = w0 / z0, wc1 = w1 / z1, wc2 = w2 / z2;
        float s = (wc0 + wc1) + wc2;
        wc0 = wc0 / s; wc1 = wc1 / s; wc2 = wc2 / s;
        const float* c = fc + (size_t)bestId * 9;
        r = (wc0 * c[0] + wc1 * c[3]) + wc2 * c[6];
        g = (wc0 * c[1] + wc1 * c[4]) + wc2 * c[7];
        b = (wc0 * c[2] + wc1 * c[5]) + wc2 * c[8];
        depthOut = (wc0 * z0 + wc1 * z1) + wc2 * z2;
    }
    out[0 * HH * WW + p] = r;
    out[1 * HH * WW + p] = g;
    out[2 * HH * WW + p] = b;
    if (write_bufs) {
        out[3 * HH * WW + p] = (float)bestId;
        out[4 * HH * WW + p] = depthOut;
    }
}

extern "C" void kernel_launch(void* const* d_in, const int* in_sizes, int n_in,
                              void* d_out, int out_size, void* d_ws, size_t ws_size,
                              hipStream_t stream) {
    const float* fv = (const float*)d_in[0];
    const float* fc = (const float*)d_in[1];
    int F = in_sizes[0] / 9;
    float* out = (float*)d_out;
    int write_bufs = (out_size >= 5 * HH * WW) ? 1 : 0;

    unsigned long long* pixbuf = (unsigned long long*)d_ws;  // 512 KB

    hipMemsetAsync(pixbuf, 0xFF, (size_t)HH * WW * 8, stream);
    int waves_per_block = 4;  // 256 threads
    int nblocks = (F + waves_per_block - 1) / waves_per_block;
    scatter_faces<<<nblocks, 256, 0, stream>>>(fv, F, pixbuf);
    shade<<<(HH * WW + 255) / 256, 256, 0, stream>>>(fv, fc, pixbuf, out, write_bufs);
}